// Round 4
// baseline (831.109 us; speedup 1.0000x reference)
//
#include <hip/hip_runtime.h>
#include <hip/hip_bf16.h>

#define HIDDEN 128
#define SCAN_TILE 1024     // elements per scan block (256 threads x 4)
#define SCAN_BLOCK 256     // threads per scan block

// ---------------------------------------------------------------------------
// CSR build step 1: zero row counters
// ---------------------------------------------------------------------------
__global__ void zero_counts(int* __restrict__ counts, int n) {
    int i = blockIdx.x * blockDim.x + threadIdx.x;
    int stride = gridDim.x * blockDim.x;
    for (; i < n; i += stride) counts[i] = 0;
}

// CSR build step 2: histogram of row degrees
__global__ void hist_kernel(const int* __restrict__ rows, int* __restrict__ counts, int E) {
    int i = blockIdx.x * blockDim.x + threadIdx.x;
    int stride = gridDim.x * blockDim.x;
    for (; i < E; i += stride) atomicAdd(&counts[rows[i]], 1);
}

// ---------------------------------------------------------------------------
// CSR build step 3: hierarchical exclusive scan.
// Stage A: per-block partial sums (coalesced int4 loads, tree reduce)
// ---------------------------------------------------------------------------
__global__ void scan_partial_sums(const int* __restrict__ counts,
                                  int* __restrict__ block_sums,
                                  int n) {
    __shared__ int sdata[SCAN_BLOCK];
    int t = threadIdx.x;
    int idx = blockIdx.x * SCAN_TILE + t * 4;
    int s = 0;
    if (idx + 3 < n) {
        int4 c = *reinterpret_cast<const int4*>(counts + idx);
        s = c.x + c.y + c.z + c.w;
    } else if (idx < n) {
        s = counts[idx];
        if (idx + 1 < n) s += counts[idx + 1];
        if (idx + 2 < n) s += counts[idx + 2];
    }
    sdata[t] = s;
    __syncthreads();
    for (int off = SCAN_BLOCK / 2; off > 0; off >>= 1) {
        if (t < off) sdata[t] += sdata[t + off];
        __syncthreads();
    }
    if (t == 0) block_sums[blockIdx.x] = sdata[0];
}

// Stage B: single small block scans the block sums in place (exclusive),
// writes row_ptr[n] = total edge count.
__global__ void scan_block_offsets(int* __restrict__ block_sums,
                                   int* __restrict__ row_ptr,
                                   int nb, int n) {
    __shared__ int sdata[SCAN_BLOCK];
    int t = threadIdx.x;
    int chunk = (nb + SCAN_BLOCK - 1) / SCAN_BLOCK;
    int lo = t * chunk;
    int hi = min(lo + chunk, nb);
    int s = 0;
    for (int i = lo; i < hi; ++i) s += block_sums[i];
    sdata[t] = s;
    __syncthreads();
    for (int off = 1; off < SCAN_BLOCK; off <<= 1) {
        int u = (t >= off) ? sdata[t - off] : 0;
        __syncthreads();
        sdata[t] += u;
        __syncthreads();
    }
    int run = sdata[t] - s;   // exclusive prefix of this thread's chunk
    for (int i = lo; i < hi; ++i) {
        int v = block_sums[i];
        block_sums[i] = run;
        run += v;
    }
    if (t == SCAN_BLOCK - 1) row_ptr[n] = sdata[SCAN_BLOCK - 1];
}

// Stage C: re-read counts, block-local exclusive scan + block offset,
// write row_ptr and cursor. counts/cursor alias (in-place) -> no __restrict__.
__global__ void scan_apply(const int* counts,
                           const int* __restrict__ block_offsets,
                           int* __restrict__ row_ptr,
                           int* cursor,
                           int n) {
    __shared__ int sdata[SCAN_BLOCK];
    int t = threadIdx.x;
    int idx = blockIdx.x * SCAN_TILE + t * 4;
    int v0 = 0, v1 = 0, v2 = 0, v3 = 0;
    if (idx + 3 < n) {
        int4 c = *reinterpret_cast<const int4*>(counts + idx);
        v0 = c.x; v1 = c.y; v2 = c.z; v3 = c.w;
    } else if (idx < n) {
        v0 = counts[idx];
        if (idx + 1 < n) v1 = counts[idx + 1];
        if (idx + 2 < n) v2 = counts[idx + 2];
    }
    int s = v0 + v1 + v2 + v3;
    sdata[t] = s;
    __syncthreads();
    for (int off = 1; off < SCAN_BLOCK; off <<= 1) {
        int u = (t >= off) ? sdata[t - off] : 0;
        __syncthreads();
        sdata[t] += u;
        __syncthreads();
    }
    int run = sdata[t] - s + block_offsets[blockIdx.x];
    if (idx < n)     { row_ptr[idx]     = run; cursor[idx]     = run; run += v0; }
    if (idx + 1 < n) { row_ptr[idx + 1] = run; cursor[idx + 1] = run; run += v1; }
    if (idx + 2 < n) { row_ptr[idx + 2] = run; cursor[idx + 2] = run; run += v2; }
    if (idx + 3 < n) { row_ptr[idx + 3] = run; cursor[idx + 3] = run; run += v3; }
}

// CSR build step 4: scatter edges into CSR slots.
// (col,val) interleaved as int2 -> ONE 8B scattered write per edge
// instead of two 4B writes to separate arrays.
__global__ void scatter_kernel(const int* __restrict__ rows,
                               const int* __restrict__ cols,
                               const float* __restrict__ vals,
                               int* __restrict__ cursor,
                               int2* __restrict__ colval,
                               int E) {
    int i = blockIdx.x * blockDim.x + threadIdx.x;
    int stride = gridDim.x * blockDim.x;
    for (; i < E; i += stride) {
        int r = rows[i];
        int pos = atomicAdd(&cursor[r], 1);
        colval[pos] = make_int2(cols[i], __float_as_int(vals[i]));
    }
}

// ---------------------------------------------------------------------------
// CSR SpMM: 16 lanes per row (avg degree = 16), 4 rows per wave.
// Each lane owns float8 (2x float4) of the hidden dim; a row gather is
// 16 lanes x 32 B = 512 B contiguous. Edge (col,val) loaded as one int2,
// broadcast within the 16-lane group via __shfl(width=16). No atomics.
// MODE 0: plain y = A*x
// MODE 1: + fused S0 = x copy (own row, coalesced) -- layer 1, x = item_emb
// MODE 2: + fused t = s0+s1+s2+acc -- layer 3
// ---------------------------------------------------------------------------
template <int MODE>
__global__ void spmm_csr16(const int* __restrict__ row_ptr,
                           const int2* __restrict__ colval,
                           const float* __restrict__ x,
                           float* __restrict__ y,
                           const float* __restrict__ s0,
                           const float* __restrict__ s1,
                           const float* __restrict__ s2,
                           float* __restrict__ aux,   // MODE1: S0 out; MODE2: T out
                           int n_rows) {
    int tid = (int)((size_t)blockIdx.x * blockDim.x + threadIdx.x);
    int row = tid >> 4;            // 16 lanes per row
    int li  = threadIdx.x & 15;
    if (row >= n_rows) return;

    int start = row_ptr[row];
    int end   = row_ptr[row + 1];

    const float4* X4 = (const float4*)x;
    float4 acc0 = make_float4(0.f, 0.f, 0.f, 0.f);
    float4 acc1 = make_float4(0.f, 0.f, 0.f, 0.f);

    for (int base = start; base < end; base += 16) {
        int idx = base + li;
        int c = 0; float v = 0.f;
        if (idx < end) {
            int2 cv = colval[idx];
            c = cv.x;
            v = __int_as_float(cv.y);
        }
        int n = min(16, end - base);
        #pragma unroll 4
        for (int j = 0; j < n; ++j) {
            int   cj = __shfl(c, j, 16);
            float vj = __shfl(v, j, 16);
            size_t b = (size_t)cj * 32 + (size_t)(li * 2);
            float4 x0 = X4[b];
            float4 x1 = X4[b + 1];
            acc0.x += vj * x0.x; acc0.y += vj * x0.y;
            acc0.z += vj * x0.z; acc0.w += vj * x0.w;
            acc1.x += vj * x1.x; acc1.y += vj * x1.y;
            acc1.z += vj * x1.z; acc1.w += vj * x1.w;
        }
    }

    size_t ob = (size_t)row * 32 + (size_t)(li * 2);
    ((float4*)y)[ob]     = acc0;
    ((float4*)y)[ob + 1] = acc1;

    if (MODE == 1) {
        // own-row coalesced copy: S0 = item_emb
        float4 a0 = X4[ob];
        float4 a1 = X4[ob + 1];
        ((float4*)aux)[ob]     = a0;
        ((float4*)aux)[ob + 1] = a1;
    }
    if (MODE == 2) {
        float4 a0 = ((const float4*)s0)[ob], a1 = ((const float4*)s0)[ob + 1];
        float4 b0 = ((const float4*)s1)[ob], b1 = ((const float4*)s1)[ob + 1];
        float4 c0 = ((const float4*)s2)[ob], c1 = ((const float4*)s2)[ob + 1];
        float4 t0, t1;
        t0.x = a0.x + b0.x + c0.x + acc0.x;
        t0.y = a0.y + b0.y + c0.y + acc0.y;
        t0.z = a0.z + b0.z + c0.z + acc0.z;
        t0.w = a0.w + b0.w + c0.w + acc0.w;
        t1.x = a1.x + b1.x + c1.x + acc1.x;
        t1.y = a1.y + b1.y + c1.y + acc1.y;
        t1.z = a1.z + b1.z + c1.z + acc1.z;
        t1.w = a1.w + b1.w + c1.w + acc1.w;
        ((float4*)aux)[ob]     = t0;
        ((float4*)aux)[ob + 1] = t1;
    }
}

extern "C" void kernel_launch(void* const* d_in, const int* in_sizes, int n_in,
                              void* d_out, int out_size, void* d_ws, size_t ws_size,
                              hipStream_t stream) {
    const float* item_emb = (const float*)d_in[0];
    const int*   adj_rows = (const int*)d_in[1];
    const int*   adj_cols = (const int*)d_in[2];
    const float* adj_vals = (const float*)d_in[3];

    const size_t NH = (size_t)in_sizes[0];      // N * 128
    const int    E  = in_sizes[1];              // 1,600,000
    const int    N  = (int)(NH / HIDDEN);       // 100,000

    // d_out layout: [ total | S0 | S1 | S2 | S3 ], each NH floats
    float* T  = (float*)d_out;
    float* S0 = T + NH;
    float* S1 = S0 + NH;
    float* S2 = S1 + NH;
    float* S3 = S2 + NH;

    // Workspace layout — byte-identical footprint to the baseline kernel.
    // csr_col (E ints) and csr_val (E floats) were adjacent 16B-aligned
    // blocks; reuse the SAME bytes as one interleaved int2 array of E elems.
    char* ws = (char*)d_ws;
    int*   row_ptr = (int*)ws;                       ws += ((size_t)(N + 1) * 4 + 15) & ~15ull;
    int*   cursor  = (int*)ws;                       ws += ((size_t)N * 4 + 15) & ~15ull;
    int2*  colval  = (int2*)ws;                      // spans old csr_col + csr_val (E*8 bytes)

    const int nb = (N + SCAN_TILE - 1) / SCAN_TILE;  // 98 scan blocks

    // block_sums scratch (nb ints): tail of the colval region. colval is only
    // written by scatter_kernel, stream-ordered AFTER scan_apply's last read.
    int* block_sums = (int*)(colval + E) - nb;

    // ---- CSR build ----
    {
        int block = 256;
        int gridN = min((N + block - 1) / block, 4096);
        int gridE = min((E + block - 1) / block, 8192);
        zero_counts<<<gridN, block, 0, stream>>>(cursor, N);              // cursor as counts
        hist_kernel<<<gridE, block, 0, stream>>>(adj_rows, cursor, E);
        scan_partial_sums<<<nb, SCAN_BLOCK, 0, stream>>>(cursor, block_sums, N);
        scan_block_offsets<<<1, SCAN_BLOCK, 0, stream>>>(block_sums, row_ptr, nb, N);
        scan_apply<<<nb, SCAN_BLOCK, 0, stream>>>(cursor, block_sums, row_ptr, cursor, N);
        scatter_kernel<<<gridE, block, 0, stream>>>(adj_rows, adj_cols, adj_vals,
                                                    cursor, colval, E);
    }

    // ---- SpMM layers (S0 copy fused into layer 1) ----
    {
        int block = 256;                       // 16 rows per block (16 lanes each)
        int grid = (N * 16 + block - 1) / block;
        spmm_csr16<1><<<grid, block, 0, stream>>>(row_ptr, colval, item_emb, S1,
                                                  nullptr, nullptr, nullptr, S0, N);
        spmm_csr16<0><<<grid, block, 0, stream>>>(row_ptr, colval, S1, S2,
                                                  nullptr, nullptr, nullptr, nullptr, N);
        spmm_csr16<2><<<grid, block, 0, stream>>>(row_ptr, colval, S2, S3,
                                                  S0, S1, S2, T, N);
    }
}

// Round 5
// 698.523 us; speedup vs baseline: 1.1898x; 1.1898x over previous
//
#include <hip/hip_runtime.h>
#include <hip/hip_fp16.h>

#define HIDDEN 128
#define SCAN_TILE 1024     // elements per scan block (256 threads x 4)
#define SCAN_BLOCK 256     // threads per scan block

// ---------------------------------------------------------------------------
// CSR build step 1: zero row counters
// ---------------------------------------------------------------------------
__global__ void zero_counts(int* __restrict__ counts, int n) {
    int i = blockIdx.x * blockDim.x + threadIdx.x;
    int stride = gridDim.x * blockDim.x;
    for (; i < n; i += stride) counts[i] = 0;
}

// CSR build step 2: histogram of row degrees
__global__ void hist_kernel(const int* __restrict__ rows, int* __restrict__ counts, int E) {
    int i = blockIdx.x * blockDim.x + threadIdx.x;
    int stride = gridDim.x * blockDim.x;
    for (; i < E; i += stride) atomicAdd(&counts[rows[i]], 1);
}

// ---------------------------------------------------------------------------
// CSR build step 3: hierarchical exclusive scan.
// ---------------------------------------------------------------------------
__global__ void scan_partial_sums(const int* __restrict__ counts,
                                  int* __restrict__ block_sums,
                                  int n) {
    __shared__ int sdata[SCAN_BLOCK];
    int t = threadIdx.x;
    int idx = blockIdx.x * SCAN_TILE + t * 4;
    int s = 0;
    if (idx + 3 < n) {
        int4 c = *reinterpret_cast<const int4*>(counts + idx);
        s = c.x + c.y + c.z + c.w;
    } else if (idx < n) {
        s = counts[idx];
        if (idx + 1 < n) s += counts[idx + 1];
        if (idx + 2 < n) s += counts[idx + 2];
    }
    sdata[t] = s;
    __syncthreads();
    for (int off = SCAN_BLOCK / 2; off > 0; off >>= 1) {
        if (t < off) sdata[t] += sdata[t + off];
        __syncthreads();
    }
    if (t == 0) block_sums[blockIdx.x] = sdata[0];
}

__global__ void scan_block_offsets(int* __restrict__ block_sums,
                                   int* __restrict__ row_ptr,
                                   int nb, int n) {
    __shared__ int sdata[SCAN_BLOCK];
    int t = threadIdx.x;
    int chunk = (nb + SCAN_BLOCK - 1) / SCAN_BLOCK;
    int lo = t * chunk;
    int hi = min(lo + chunk, nb);
    int s = 0;
    for (int i = lo; i < hi; ++i) s += block_sums[i];
    sdata[t] = s;
    __syncthreads();
    for (int off = 1; off < SCAN_BLOCK; off <<= 1) {
        int u = (t >= off) ? sdata[t - off] : 0;
        __syncthreads();
        sdata[t] += u;
        __syncthreads();
    }
    int run = sdata[t] - s;
    for (int i = lo; i < hi; ++i) {
        int v = block_sums[i];
        block_sums[i] = run;
        run += v;
    }
    if (t == SCAN_BLOCK - 1) row_ptr[n] = sdata[SCAN_BLOCK - 1];
}

// counts/cursor alias (in-place) -> no __restrict__ on them.
__global__ void scan_apply(const int* counts,
                           const int* __restrict__ block_offsets,
                           int* __restrict__ row_ptr,
                           int* cursor,
                           int n) {
    __shared__ int sdata[SCAN_BLOCK];
    int t = threadIdx.x;
    int idx = blockIdx.x * SCAN_TILE + t * 4;
    int v0 = 0, v1 = 0, v2 = 0, v3 = 0;
    if (idx + 3 < n) {
        int4 c = *reinterpret_cast<const int4*>(counts + idx);
        v0 = c.x; v1 = c.y; v2 = c.z; v3 = c.w;
    } else if (idx < n) {
        v0 = counts[idx];
        if (idx + 1 < n) v1 = counts[idx + 1];
        if (idx + 2 < n) v2 = counts[idx + 2];
    }
    int s = v0 + v1 + v2 + v3;
    sdata[t] = s;
    __syncthreads();
    for (int off = 1; off < SCAN_BLOCK; off <<= 1) {
        int u = (t >= off) ? sdata[t - off] : 0;
        __syncthreads();
        sdata[t] += u;
        __syncthreads();
    }
    int run = sdata[t] - s + block_offsets[blockIdx.x];
    if (idx < n)     { row_ptr[idx]     = run; cursor[idx]     = run; run += v0; }
    if (idx + 1 < n) { row_ptr[idx + 1] = run; cursor[idx + 1] = run; run += v1; }
    if (idx + 2 < n) { row_ptr[idx + 2] = run; cursor[idx + 2] = run; run += v2; }
    if (idx + 3 < n) { row_ptr[idx + 3] = run; cursor[idx + 3] = run; run += v3; }
}

// CSR build step 4: scatter edges; (col,val) interleaved as int2.
__global__ void scatter_kernel(const int* __restrict__ rows,
                               const int* __restrict__ cols,
                               const float* __restrict__ vals,
                               int* __restrict__ cursor,
                               int2* __restrict__ colval,
                               int E) {
    int i = blockIdx.x * blockDim.x + threadIdx.x;
    int stride = gridDim.x * blockDim.x;
    for (; i < E; i += stride) {
        int r = rows[i];
        int pos = atomicAdd(&cursor[r], 1);
        colval[pos] = make_int2(cols[i], __float_as_int(vals[i]));
    }
}

// ---------------------------------------------------------------------------
// conv0: S0 = item_emb (fp32 copy) AND X0h = fp16(item_emb) shadow.
// One thread handles 8 floats: 2 float4 reads, 2 float4 writes, 1 float4
// (= 8 packed halfs) write.
// ---------------------------------------------------------------------------
__global__ void convert_copy(const float4* __restrict__ src,
                             float4* __restrict__ s0,
                             float4* __restrict__ xh,
                             size_t n8) {
    size_t stride = (size_t)gridDim.x * blockDim.x;
    for (size_t i = (size_t)blockIdx.x * blockDim.x + threadIdx.x; i < n8; i += stride) {
        float4 a = src[i * 2];
        float4 b = src[i * 2 + 1];
        s0[i * 2]     = a;
        s0[i * 2 + 1] = b;
        __half2 h[4];
        h[0] = __floats2half2_rn(a.x, a.y);
        h[1] = __floats2half2_rn(a.z, a.w);
        h[2] = __floats2half2_rn(b.x, b.y);
        h[3] = __floats2half2_rn(b.z, b.w);
        xh[i] = *reinterpret_cast<float4*>(h);
    }
}

// ---------------------------------------------------------------------------
// CSR SpMM with fp16 gather: 16 lanes per row, 4 rows per wave.
// Gather source xh holds fp16 rows (128 halfs = 16 float4 per row); each lane
// loads ONE float4 (8 halfs, 16 B) per edge -> 256 B per row gather (half the
// fp32 traffic). Accumulation fp32. Output y fp32; optional fp16 shadow yh
// for the next layer's gather.
// ---------------------------------------------------------------------------
template <bool WRITE_SHADOW>
__global__ void spmm_h16(const int* __restrict__ row_ptr,
                         const int2* __restrict__ colval,
                         const float4* __restrict__ xh,
                         float* __restrict__ y,
                         float4* __restrict__ yh,
                         int n_rows) {
    int tid = (int)((size_t)blockIdx.x * blockDim.x + threadIdx.x);
    int row = tid >> 4;            // 16 lanes per row
    int li  = threadIdx.x & 15;
    if (row >= n_rows) return;

    int start = row_ptr[row];
    int end   = row_ptr[row + 1];

    float acc[8] = {0.f, 0.f, 0.f, 0.f, 0.f, 0.f, 0.f, 0.f};

    for (int base = start; base < end; base += 16) {
        int idx = base + li;
        int c = 0; float v = 0.f;
        if (idx < end) {
            int2 cv = colval[idx];
            c = cv.x;
            v = __int_as_float(cv.y);
        }
        int n = min(16, end - base);
        #pragma unroll 4
        for (int j = 0; j < n; ++j) {
            int   cj = __shfl(c, j, 16);
            float vj = __shfl(v, j, 16);
            float4 h4 = xh[(size_t)cj * 16 + li];
            const __half2* hp = reinterpret_cast<const __half2*>(&h4);
            float2 f0 = __half22float2(hp[0]);
            float2 f1 = __half22float2(hp[1]);
            float2 f2 = __half22float2(hp[2]);
            float2 f3 = __half22float2(hp[3]);
            acc[0] += vj * f0.x; acc[1] += vj * f0.y;
            acc[2] += vj * f1.x; acc[3] += vj * f1.y;
            acc[4] += vj * f2.x; acc[5] += vj * f2.y;
            acc[6] += vj * f3.x; acc[7] += vj * f3.y;
        }
    }

    size_t ob = (size_t)row * 32 + (size_t)(li * 2);   // float4 index
    ((float4*)y)[ob]     = make_float4(acc[0], acc[1], acc[2], acc[3]);
    ((float4*)y)[ob + 1] = make_float4(acc[4], acc[5], acc[6], acc[7]);

    if (WRITE_SHADOW) {
        __half2 h[4];
        h[0] = __floats2half2_rn(acc[0], acc[1]);
        h[1] = __floats2half2_rn(acc[2], acc[3]);
        h[2] = __floats2half2_rn(acc[4], acc[5]);
        h[3] = __floats2half2_rn(acc[6], acc[7]);
        yh[(size_t)row * 16 + li] = *reinterpret_cast<float4*>(h);
    }
}

// ---------------------------------------------------------------------------
// Final total: T = S0 + S1 + S2 + S3 (elementwise, float4, grid-stride)
// ---------------------------------------------------------------------------
__global__ void total_kernel(const float4* __restrict__ s0,
                             const float4* __restrict__ s1,
                             const float4* __restrict__ s2,
                             const float4* __restrict__ s3,
                             float4* __restrict__ t,
                             size_t n4) {
    size_t stride = (size_t)gridDim.x * blockDim.x;
    for (size_t i = (size_t)blockIdx.x * blockDim.x + threadIdx.x; i < n4; i += stride) {
        float4 a = s0[i], b = s1[i], c = s2[i], d = s3[i];
        float4 o;
        o.x = a.x + b.x + c.x + d.x;
        o.y = a.y + b.y + c.y + d.y;
        o.z = a.z + b.z + c.z + d.z;
        o.w = a.w + b.w + c.w + d.w;
        t[i] = o;
    }
}

extern "C" void kernel_launch(void* const* d_in, const int* in_sizes, int n_in,
                              void* d_out, int out_size, void* d_ws, size_t ws_size,
                              hipStream_t stream) {
    const float* item_emb = (const float*)d_in[0];
    const int*   adj_rows = (const int*)d_in[1];
    const int*   adj_cols = (const int*)d_in[2];
    const float* adj_vals = (const float*)d_in[3];

    const size_t NH = (size_t)in_sizes[0];      // N * 128
    const int    E  = in_sizes[1];              // 1,600,000
    const int    N  = (int)(NH / HIDDEN);       // 100,000

    // d_out layout: [ total | S0 | S1 | S2 | S3 ], each NH floats
    float* T  = (float*)d_out;
    float* S0 = T + NH;
    float* S1 = S0 + NH;
    float* S2 = S1 + NH;
    float* S3 = S2 + NH;

    // fp16 shadow placement (NO workspace growth; stream-order-disjoint
    // lifetimes within d_out):
    //   shA (T region, 2NH bytes of 4NH):  X0h during layer 1, then S2h
    //        during layer 3. T itself is written only by total_kernel (last).
    //   shB (S3 region): S1h during layer 2; dead before layer 3 overwrites
    //        the region with fp32 S3.
    float4* shA = (float4*)T;
    float4* shB = (float4*)S3;

    // Workspace layout — byte-identical footprint to the baseline kernel.
    char* ws = (char*)d_ws;
    int*   row_ptr = (int*)ws;                       ws += ((size_t)(N + 1) * 4 + 15) & ~15ull;
    int*   cursor  = (int*)ws;                       ws += ((size_t)N * 4 + 15) & ~15ull;
    int2*  colval  = (int2*)ws;                      // E*8 bytes (old csr_col+csr_val)

    const int nb = (N + SCAN_TILE - 1) / SCAN_TILE;  // 98 scan blocks
    int* block_sums = (int*)(colval + E) - nb;       // tail of colval, dead before scatter

    // ---- CSR build ----
    {
        int block = 256;
        int gridN = min((N + block - 1) / block, 4096);
        int gridE = min((E + block - 1) / block, 8192);
        zero_counts<<<gridN, block, 0, stream>>>(cursor, N);
        hist_kernel<<<gridE, block, 0, stream>>>(adj_rows, cursor, E);
        scan_partial_sums<<<nb, SCAN_BLOCK, 0, stream>>>(cursor, block_sums, N);
        scan_block_offsets<<<1, SCAN_BLOCK, 0, stream>>>(block_sums, row_ptr, nb, N);
        scan_apply<<<nb, SCAN_BLOCK, 0, stream>>>(cursor, block_sums, row_ptr, cursor, N);
        scatter_kernel<<<gridE, block, 0, stream>>>(adj_rows, adj_cols, adj_vals,
                                                    cursor, colval, E);
    }

    // ---- S0 copy + fp16(item_emb) shadow ----
    {
        size_t n8 = NH / 8;
        int block = 256;
        int grid = (int)min((n8 + block - 1) / block, (size_t)8192);
        convert_copy<<<grid, block, 0, stream>>>((const float4*)item_emb,
                                                 (float4*)S0, shA, n8);
    }

    // ---- SpMM layers (fp16 gather, fp32 accumulate/output) ----
    {
        int block = 256;                       // 16 rows per block (16 lanes each)
        int grid = (N * 16 + block - 1) / block;
        // L1: gather X0h (shA) -> S1 fp32 + S1h (shB)
        spmm_h16<true><<<grid, block, 0, stream>>>(row_ptr, colval, shA, S1, shB, N);
        // L2: gather S1h (shB) -> S2 fp32 + S2h (shA, over dead X0h)
        spmm_h16<true><<<grid, block, 0, stream>>>(row_ptr, colval, shB, S2, shA, N);
        // L3: gather S2h (shA) -> S3 fp32 (overwrites dead S1h region)
        spmm_h16<false><<<grid, block, 0, stream>>>(row_ptr, colval, shA, S3, nullptr, N);
    }

    // ---- T = S0 + S1 + S2 + S3 (overwrites dead S2h region) ----
    {
        size_t n4 = NH / 4;
        int block = 256;
        int grid = (int)min((n4 + block - 1) / block, (size_t)8192);
        total_kernel<<<grid, block, 0, stream>>>((const float4*)S0, (const float4*)S1,
                                                 (const float4*)S2, (const float4*)S3,
                                                 (float4*)T, n4);
    }
}

// Round 7
// 634.885 us; speedup vs baseline: 1.3091x; 1.1002x over previous
//
#include <hip/hip_runtime.h>
#include <hip/hip_fp16.h>

#define HIDDEN 128
#define SCAN_TILE 1024     // elements per scan block (256 threads x 4)
#define SCAN_BLOCK 256     // threads per scan block

// ---------------------------------------------------------------------------
// nontemporal helpers: __builtin_nontemporal_* wants a clang vector type,
// not HIP_vector_type<float,4>. ext_vector_type(4) is layout-identical.
// Keeps fp32-only streams out of L3 so the fp16 gather shadows + colval
// stay resident (full working set > 256 MB L3).
// ---------------------------------------------------------------------------
typedef float cvec4 __attribute__((ext_vector_type(4)));

__device__ inline void nt_store4(float4* p, float4 v) {
    cvec4 x; x.x = v.x; x.y = v.y; x.z = v.z; x.w = v.w;
    __builtin_nontemporal_store(x, reinterpret_cast<cvec4*>(p));
}
__device__ inline float4 nt_load4(const float4* p) {
    cvec4 x = __builtin_nontemporal_load(reinterpret_cast<const cvec4*>(p));
    return make_float4(x.x, x.y, x.z, x.w);
}

// ---------------------------------------------------------------------------
// CSR build step 1: zero row counters
// ---------------------------------------------------------------------------
__global__ void zero_counts(int* __restrict__ counts, int n) {
    int i = blockIdx.x * blockDim.x + threadIdx.x;
    int stride = gridDim.x * blockDim.x;
    for (; i < n; i += stride) counts[i] = 0;
}

// CSR build step 2: histogram of row degrees; atomicAdd's return value IS
// the edge's rank within its row -> store it, so scatter needs no atomics.
__global__ void hist_kernel(const int* __restrict__ rows,
                            int* __restrict__ counts,
                            int* __restrict__ rank,
                            int E) {
    int i = blockIdx.x * blockDim.x + threadIdx.x;
    int stride = gridDim.x * blockDim.x;
    for (; i < E; i += stride) rank[i] = atomicAdd(&counts[rows[i]], 1);
}

// ---------------------------------------------------------------------------
// CSR build step 3: hierarchical exclusive scan.
// ---------------------------------------------------------------------------
__global__ void scan_partial_sums(const int* __restrict__ counts,
                                  int* __restrict__ block_sums,
                                  int n) {
    __shared__ int sdata[SCAN_BLOCK];
    int t = threadIdx.x;
    int idx = blockIdx.x * SCAN_TILE + t * 4;
    int s = 0;
    if (idx + 3 < n) {
        int4 c = *reinterpret_cast<const int4*>(counts + idx);
        s = c.x + c.y + c.z + c.w;
    } else if (idx < n) {
        s = counts[idx];
        if (idx + 1 < n) s += counts[idx + 1];
        if (idx + 2 < n) s += counts[idx + 2];
    }
    sdata[t] = s;
    __syncthreads();
    for (int off = SCAN_BLOCK / 2; off > 0; off >>= 1) {
        if (t < off) sdata[t] += sdata[t + off];
        __syncthreads();
    }
    if (t == 0) block_sums[blockIdx.x] = sdata[0];
}

__global__ void scan_block_offsets(int* __restrict__ block_sums,
                                   int* __restrict__ row_ptr,
                                   int nb, int n) {
    __shared__ int sdata[SCAN_BLOCK];
    int t = threadIdx.x;
    int chunk = (nb + SCAN_BLOCK - 1) / SCAN_BLOCK;
    int lo = t * chunk;
    int hi = min(lo + chunk, nb);
    int s = 0;
    for (int i = lo; i < hi; ++i) s += block_sums[i];
    sdata[t] = s;
    __syncthreads();
    for (int off = 1; off < SCAN_BLOCK; off <<= 1) {
        int u = (t >= off) ? sdata[t - off] : 0;
        __syncthreads();
        sdata[t] += u;
        __syncthreads();
    }
    int run = sdata[t] - s;
    for (int i = lo; i < hi; ++i) {
        int v = block_sums[i];
        block_sums[i] = run;
        run += v;
    }
    if (t == SCAN_BLOCK - 1) row_ptr[n] = sdata[SCAN_BLOCK - 1];
}

// Stage C: exclusive scan of counts -> row_ptr only (no cursor needed with
// rank-based scatter). counts is read-only here.
__global__ void scan_apply(const int* __restrict__ counts,
                           const int* __restrict__ block_offsets,
                           int* __restrict__ row_ptr,
                           int n) {
    __shared__ int sdata[SCAN_BLOCK];
    int t = threadIdx.x;
    int idx = blockIdx.x * SCAN_TILE + t * 4;
    int v0 = 0, v1 = 0, v2 = 0, v3 = 0;
    if (idx + 3 < n) {
        int4 c = *reinterpret_cast<const int4*>(counts + idx);
        v0 = c.x; v1 = c.y; v2 = c.z; v3 = c.w;
    } else if (idx < n) {
        v0 = counts[idx];
        if (idx + 1 < n) v1 = counts[idx + 1];
        if (idx + 2 < n) v2 = counts[idx + 2];
    }
    int s = v0 + v1 + v2 + v3;
    sdata[t] = s;
    __syncthreads();
    for (int off = 1; off < SCAN_BLOCK; off <<= 1) {
        int u = (t >= off) ? sdata[t - off] : 0;
        __syncthreads();
        sdata[t] += u;
        __syncthreads();
    }
    int run = sdata[t] - s + block_offsets[blockIdx.x];
    if (idx < n)     { row_ptr[idx]     = run; run += v0; }
    if (idx + 1 < n) { row_ptr[idx + 1] = run; run += v1; }
    if (idx + 2 < n) { row_ptr[idx + 2] = run; run += v2; }
    if (idx + 3 < n) { row_ptr[idx + 3] = run; run += v3; }
}

// CSR build step 4: scatter edges using precomputed rank — NO atomics.
// row_ptr table is 0.4 MB -> L2-resident; rank read is coalesced.
__global__ void scatter_kernel(const int* __restrict__ rows,
                               const int* __restrict__ cols,
                               const float* __restrict__ vals,
                               const int* __restrict__ row_ptr,
                               const int* __restrict__ rank,
                               int2* __restrict__ colval,
                               int E) {
    int i = blockIdx.x * blockDim.x + threadIdx.x;
    int stride = gridDim.x * blockDim.x;
    for (; i < E; i += stride) {
        int pos = row_ptr[rows[i]] + rank[i];
        colval[pos] = make_int2(cols[i], __float_as_int(vals[i]));
    }
}

// ---------------------------------------------------------------------------
// conv0: S0 = item_emb (fp32, nontemporal both ways) AND X0h = fp16 shadow
// (normal store -> cached, it is layer 1's gather source).
// ---------------------------------------------------------------------------
__global__ void convert_copy(const float4* __restrict__ src,
                             float4* __restrict__ s0,
                             float4* __restrict__ xh,
                             size_t n8) {
    size_t stride = (size_t)gridDim.x * blockDim.x;
    for (size_t i = (size_t)blockIdx.x * blockDim.x + threadIdx.x; i < n8; i += stride) {
        float4 a = nt_load4(src + i * 2);
        float4 b = nt_load4(src + i * 2 + 1);
        nt_store4(s0 + i * 2, a);
        nt_store4(s0 + i * 2 + 1, b);
        __half2 h[4];
        h[0] = __floats2half2_rn(a.x, a.y);
        h[1] = __floats2half2_rn(a.z, a.w);
        h[2] = __floats2half2_rn(b.x, b.y);
        h[3] = __floats2half2_rn(b.z, b.w);
        xh[i] = *reinterpret_cast<float4*>(h);
    }
}

// ---------------------------------------------------------------------------
// CSR SpMM with fp16 gather: 16 lanes per row, 4 rows per wave.
// fp32 y written nontemporal (only total_kernel re-reads it, once);
// fp16 shadow written normal (next layer's gather source, keep in L3).
// ---------------------------------------------------------------------------
template <bool WRITE_SHADOW>
__global__ void spmm_h16(const int* __restrict__ row_ptr,
                         const int2* __restrict__ colval,
                         const float4* __restrict__ xh,
                         float* __restrict__ y,
                         float4* __restrict__ yh,
                         int n_rows) {
    int tid = (int)((size_t)blockIdx.x * blockDim.x + threadIdx.x);
    int row = tid >> 4;            // 16 lanes per row
    int li  = threadIdx.x & 15;
    if (row >= n_rows) return;

    int start = row_ptr[row];
    int end   = row_ptr[row + 1];

    float acc[8] = {0.f, 0.f, 0.f, 0.f, 0.f, 0.f, 0.f, 0.f};

    for (int base = start; base < end; base += 16) {
        int idx = base + li;
        int c = 0; float v = 0.f;
        if (idx < end) {
            int2 cv = colval[idx];
            c = cv.x;
            v = __int_as_float(cv.y);
        }
        int n = min(16, end - base);
        #pragma unroll 4
        for (int j = 0; j < n; ++j) {
            int   cj = __shfl(c, j, 16);
            float vj = __shfl(v, j, 16);
            float4 h4 = xh[(size_t)cj * 16 + li];
            const __half2* hp = reinterpret_cast<const __half2*>(&h4);
            float2 f0 = __half22float2(hp[0]);
            float2 f1 = __half22float2(hp[1]);
            float2 f2 = __half22float2(hp[2]);
            float2 f3 = __half22float2(hp[3]);
            acc[0] += vj * f0.x; acc[1] += vj * f0.y;
            acc[2] += vj * f1.x; acc[3] += vj * f1.y;
            acc[4] += vj * f2.x; acc[5] += vj * f2.y;
            acc[6] += vj * f3.x; acc[7] += vj * f3.y;
        }
    }

    size_t ob = (size_t)row * 32 + (size_t)(li * 2);   // float4 index
    nt_store4((float4*)y + ob,     make_float4(acc[0], acc[1], acc[2], acc[3]));
    nt_store4((float4*)y + ob + 1, make_float4(acc[4], acc[5], acc[6], acc[7]));

    if (WRITE_SHADOW) {
        __half2 h[4];
        h[0] = __floats2half2_rn(acc[0], acc[1]);
        h[1] = __floats2half2_rn(acc[2], acc[3]);
        h[2] = __floats2half2_rn(acc[4], acc[5]);
        h[3] = __floats2half2_rn(acc[6], acc[7]);
        yh[(size_t)row * 16 + li] = *reinterpret_cast<float4*>(h);
    }
}

// ---------------------------------------------------------------------------
// Final total: T = S0 + S1 + S2 + S3 (pure streaming -> fully nontemporal)
// ---------------------------------------------------------------------------
__global__ void total_kernel(const float4* __restrict__ s0,
                             const float4* __restrict__ s1,
                             const float4* __restrict__ s2,
                             const float4* __restrict__ s3,
                             float4* __restrict__ t,
                             size_t n4) {
    size_t stride = (size_t)gridDim.x * blockDim.x;
    for (size_t i = (size_t)blockIdx.x * blockDim.x + threadIdx.x; i < n4; i += stride) {
        float4 a = nt_load4(s0 + i), b = nt_load4(s1 + i);
        float4 c = nt_load4(s2 + i), d = nt_load4(s3 + i);
        float4 o;
        o.x = a.x + b.x + c.x + d.x;
        o.y = a.y + b.y + c.y + d.y;
        o.z = a.z + b.z + c.z + d.z;
        o.w = a.w + b.w + c.w + d.w;
        nt_store4(t + i, o);
    }
}

extern "C" void kernel_launch(void* const* d_in, const int* in_sizes, int n_in,
                              void* d_out, int out_size, void* d_ws, size_t ws_size,
                              hipStream_t stream) {
    const float* item_emb = (const float*)d_in[0];
    const int*   adj_rows = (const int*)d_in[1];
    const int*   adj_cols = (const int*)d_in[2];
    const float* adj_vals = (const float*)d_in[3];

    const size_t NH = (size_t)in_sizes[0];      // N * 128
    const int    E  = in_sizes[1];              // 1,600,000
    const int    N  = (int)(NH / HIDDEN);       // 100,000

    // d_out layout: [ total | S0 | S1 | S2 | S3 ], each NH floats
    float* T  = (float*)d_out;
    float* S0 = T + NH;
    float* S1 = S0 + NH;
    float* S2 = S1 + NH;
    float* S3 = S2 + NH;

    // Scratch placement inside d_out (stream-order-disjoint lifetimes):
    //   shA (T region):  X0h during L1, then S2h during L3; T written last.
    //   shB (S3 region): S1h during L2; dead before L3 writes fp32 S3.
    //   rank (S1 region): used during build only; dead before L1 writes S1.
    float4* shA  = (float4*)T;
    float4* shB  = (float4*)S3;
    int*    rank = (int*)S1;                    // E ints = 6.4 MB << 51 MB

    // Workspace layout — byte-identical footprint to the baseline kernel.
    char* ws = (char*)d_ws;
    int*   row_ptr = (int*)ws;                       ws += ((size_t)(N + 1) * 4 + 15) & ~15ull;
    int*   counts  = (int*)ws;                       ws += ((size_t)N * 4 + 15) & ~15ull;
    int2*  colval  = (int2*)ws;                      // E*8 bytes (old csr_col+csr_val)

    const int nb = (N + SCAN_TILE - 1) / SCAN_TILE;  // 98 scan blocks
    int* block_sums = (int*)(colval + E) - nb;       // tail of colval, dead before scatter

    // ---- CSR build (no atomics in scatter: rank captured during hist) ----
    {
        int block = 256;
        int gridN = min((N + block - 1) / block, 4096);
        int gridE = min((E + block - 1) / block, 8192);
        zero_counts<<<gridN, block, 0, stream>>>(counts, N);
        hist_kernel<<<gridE, block, 0, stream>>>(adj_rows, counts, rank, E);
        scan_partial_sums<<<nb, SCAN_BLOCK, 0, stream>>>(counts, block_sums, N);
        scan_block_offsets<<<1, SCAN_BLOCK, 0, stream>>>(block_sums, row_ptr, nb, N);
        scan_apply<<<nb, SCAN_BLOCK, 0, stream>>>(counts, block_sums, row_ptr, N);
        scatter_kernel<<<gridE, block, 0, stream>>>(adj_rows, adj_cols, adj_vals,
                                                    row_ptr, rank, colval, E);
    }

    // ---- S0 copy + fp16(item_emb) shadow ----
    {
        size_t n8 = NH / 8;
        int block = 256;
        int grid = (int)min((n8 + block - 1) / block, (size_t)8192);
        convert_copy<<<grid, block, 0, stream>>>((const float4*)item_emb,
                                                 (float4*)S0, shA, n8);
    }

    // ---- SpMM layers (fp16 gather, fp32 accumulate/output) ----
    {
        int block = 256;                       // 16 rows per block (16 lanes each)
        int grid = (N * 16 + block - 1) / block;
        // L1: gather X0h (shA) -> S1 fp32 (overwrites dead rank) + S1h (shB)
        spmm_h16<true><<<grid, block, 0, stream>>>(row_ptr, colval, shA, S1, shB, N);
        // L2: gather S1h (shB) -> S2 fp32 + S2h (shA, over dead X0h)
        spmm_h16<true><<<grid, block, 0, stream>>>(row_ptr, colval, shB, S2, shA, N);
        // L3: gather S2h (shA) -> S3 fp32 (overwrites dead S1h region)
        spmm_h16<false><<<grid, block, 0, stream>>>(row_ptr, colval, shA, S3, nullptr, N);
    }

    // ---- T = S0 + S1 + S2 + S3 (overwrites dead S2h region) ----
    {
        size_t n4 = NH / 4;
        int block = 256;
        int grid = (int)min((n4 + block - 1) / block, (size_t)8192);
        total_kernel<<<grid, block, 0, stream>>>((const float4*)S0, (const float4*)S1,
                                                 (const float4*)S2, (const float4*)S3,
                                                 (float4*)T, n4);
    }
}

// Round 8
// 628.468 us; speedup vs baseline: 1.3224x; 1.0102x over previous
//
#include <hip/hip_runtime.h>
#include <hip/hip_fp16.h>

#define HIDDEN 128
#define SCAN_TILE 1024     // elements per scan block (256 threads x 4)
#define SCAN_BLOCK 256     // threads per scan block

// ---------------------------------------------------------------------------
// nontemporal helpers: __builtin_nontemporal_* wants a clang vector type,
// not HIP_vector_type<float,4>. ext_vector_type(4) is layout-identical.
// ---------------------------------------------------------------------------
typedef float cvec4 __attribute__((ext_vector_type(4)));

__device__ inline void nt_store4(float4* p, float4 v) {
    cvec4 x; x.x = v.x; x.y = v.y; x.z = v.z; x.w = v.w;
    __builtin_nontemporal_store(x, reinterpret_cast<cvec4*>(p));
}
__device__ inline float4 nt_load4(const float4* p) {
    cvec4 x = __builtin_nontemporal_load(reinterpret_cast<const cvec4*>(p));
    return make_float4(x.x, x.y, x.z, x.w);
}

// ---------------------------------------------------------------------------
// CSR build step 1: zero row counters
// ---------------------------------------------------------------------------
__global__ void zero_counts(int* __restrict__ counts, int n) {
    int i = blockIdx.x * blockDim.x + threadIdx.x;
    int stride = gridDim.x * blockDim.x;
    for (; i < n; i += stride) counts[i] = 0;
}

// CSR build step 2: histogram of row degrees; atomicAdd's return value IS
// the edge's rank within its row -> store it, so scatter needs no atomics.
__global__ void hist_kernel(const int* __restrict__ rows,
                            int* __restrict__ counts,
                            int* __restrict__ rank,
                            int E) {
    int i = blockIdx.x * blockDim.x + threadIdx.x;
    int stride = gridDim.x * blockDim.x;
    for (; i < E; i += stride) rank[i] = atomicAdd(&counts[rows[i]], 1);
}

// ---------------------------------------------------------------------------
// CSR build step 3: hierarchical exclusive scan.
// ---------------------------------------------------------------------------
__global__ void scan_partial_sums(const int* __restrict__ counts,
                                  int* __restrict__ block_sums,
                                  int n) {
    __shared__ int sdata[SCAN_BLOCK];
    int t = threadIdx.x;
    int idx = blockIdx.x * SCAN_TILE + t * 4;
    int s = 0;
    if (idx + 3 < n) {
        int4 c = *reinterpret_cast<const int4*>(counts + idx);
        s = c.x + c.y + c.z + c.w;
    } else if (idx < n) {
        s = counts[idx];
        if (idx + 1 < n) s += counts[idx + 1];
        if (idx + 2 < n) s += counts[idx + 2];
    }
    sdata[t] = s;
    __syncthreads();
    for (int off = SCAN_BLOCK / 2; off > 0; off >>= 1) {
        if (t < off) sdata[t] += sdata[t + off];
        __syncthreads();
    }
    if (t == 0) block_sums[blockIdx.x] = sdata[0];
}

__global__ void scan_block_offsets(int* __restrict__ block_sums,
                                   int* __restrict__ row_ptr,
                                   int nb, int n) {
    __shared__ int sdata[SCAN_BLOCK];
    int t = threadIdx.x;
    int chunk = (nb + SCAN_BLOCK - 1) / SCAN_BLOCK;
    int lo = t * chunk;
    int hi = min(lo + chunk, nb);
    int s = 0;
    for (int i = lo; i < hi; ++i) s += block_sums[i];
    sdata[t] = s;
    __syncthreads();
    for (int off = 1; off < SCAN_BLOCK; off <<= 1) {
        int u = (t >= off) ? sdata[t - off] : 0;
        __syncthreads();
        sdata[t] += u;
        __syncthreads();
    }
    int run = sdata[t] - s;
    for (int i = lo; i < hi; ++i) {
        int v = block_sums[i];
        block_sums[i] = run;
        run += v;
    }
    if (t == SCAN_BLOCK - 1) row_ptr[n] = sdata[SCAN_BLOCK - 1];
}

// Stage C: exclusive scan of counts -> row_ptr only.
__global__ void scan_apply(const int* __restrict__ counts,
                           const int* __restrict__ block_offsets,
                           int* __restrict__ row_ptr,
                           int n) {
    __shared__ int sdata[SCAN_BLOCK];
    int t = threadIdx.x;
    int idx = blockIdx.x * SCAN_TILE + t * 4;
    int v0 = 0, v1 = 0, v2 = 0, v3 = 0;
    if (idx + 3 < n) {
        int4 c = *reinterpret_cast<const int4*>(counts + idx);
        v0 = c.x; v1 = c.y; v2 = c.z; v3 = c.w;
    } else if (idx < n) {
        v0 = counts[idx];
        if (idx + 1 < n) v1 = counts[idx + 1];
        if (idx + 2 < n) v2 = counts[idx + 2];
    }
    int s = v0 + v1 + v2 + v3;
    sdata[t] = s;
    __syncthreads();
    for (int off = 1; off < SCAN_BLOCK; off <<= 1) {
        int u = (t >= off) ? sdata[t - off] : 0;
        __syncthreads();
        sdata[t] += u;
        __syncthreads();
    }
    int run = sdata[t] - s + block_offsets[blockIdx.x];
    if (idx < n)     { row_ptr[idx]     = run; run += v0; }
    if (idx + 1 < n) { row_ptr[idx + 1] = run; run += v1; }
    if (idx + 2 < n) { row_ptr[idx + 2] = run; run += v2; }
    if (idx + 3 < n) { row_ptr[idx + 3] = run; run += v3; }
}

// CSR build step 4: scatter edges using precomputed rank — NO atomics.
__global__ void scatter_kernel(const int* __restrict__ rows,
                               const int* __restrict__ cols,
                               const float* __restrict__ vals,
                               const int* __restrict__ row_ptr,
                               const int* __restrict__ rank,
                               int2* __restrict__ colval,
                               int E) {
    int i = blockIdx.x * blockDim.x + threadIdx.x;
    int stride = gridDim.x * blockDim.x;
    for (; i < E; i += stride) {
        int pos = row_ptr[rows[i]] + rank[i];
        colval[pos] = make_int2(cols[i], __float_as_int(vals[i]));
    }
}

// ---------------------------------------------------------------------------
// conv0: S0 = item_emb (fp32, nontemporal both ways) AND X0h = fp16 shadow
// (normal store -> cached, it is layer 1's gather source).
// ---------------------------------------------------------------------------
__global__ void convert_copy(const float4* __restrict__ src,
                             float4* __restrict__ s0,
                             float4* __restrict__ xh,
                             size_t n8) {
    size_t stride = (size_t)gridDim.x * blockDim.x;
    for (size_t i = (size_t)blockIdx.x * blockDim.x + threadIdx.x; i < n8; i += stride) {
        float4 a = nt_load4(src + i * 2);
        float4 b = nt_load4(src + i * 2 + 1);
        nt_store4(s0 + i * 2, a);
        nt_store4(s0 + i * 2 + 1, b);
        __half2 h[4];
        h[0] = __floats2half2_rn(a.x, a.y);
        h[1] = __floats2half2_rn(a.z, a.w);
        h[2] = __floats2half2_rn(b.x, b.y);
        h[3] = __floats2half2_rn(b.z, b.w);
        xh[i] = *reinterpret_cast<float4*>(h);
    }
}

// ---------------------------------------------------------------------------
// CSR SpMM with fp16 gather: 16 lanes per row, 4 rows per wave.
// Inner loop fully unrolled in two phases: (1) issue ALL 16 guarded gathers
// into a register array (16 loads in flight per wave, vs 4 before), then
// (2) consume with shuffled-scale FMAs. Gather was measured at ~4.1 TB/s
// effective (L3-resident source) => concurrency-limited, not BW-limited.
// ---------------------------------------------------------------------------
template <bool WRITE_SHADOW>
__global__ void spmm_h16(const int* __restrict__ row_ptr,
                         const int2* __restrict__ colval,
                         const float4* __restrict__ xh,
                         float* __restrict__ y,
                         float4* __restrict__ yh,
                         int n_rows) {
    int tid = (int)((size_t)blockIdx.x * blockDim.x + threadIdx.x);
    int row = tid >> 4;            // 16 lanes per row
    int li  = threadIdx.x & 15;
    if (row >= n_rows) return;

    int start = row_ptr[row];
    int end   = row_ptr[row + 1];

    float acc[8] = {0.f, 0.f, 0.f, 0.f, 0.f, 0.f, 0.f, 0.f};

    for (int base = start; base < end; base += 16) {
        int idx = base + li;
        int c = 0; float v = 0.f;
        if (idx < end) {
            int2 cv = colval[idx];
            c = cv.x;
            v = __int_as_float(cv.y);
        }
        int n = min(16, end - base);   // uniform within the 16-lane group

        // Phase 1: issue all gathers (predicated); h[] in registers.
        float4 h[16];
        #pragma unroll
        for (int j = 0; j < 16; ++j) {
            int cj = __shfl(c, j, 16);
            if (j < n) h[j] = xh[(size_t)cj * 16 + li];
        }

        // Phase 2: consume.
        #pragma unroll
        for (int j = 0; j < 16; ++j) {
            if (j < n) {
                float vj = __shfl(v, j, 16);
                const __half2* hp = reinterpret_cast<const __half2*>(&h[j]);
                float2 f0 = __half22float2(hp[0]);
                float2 f1 = __half22float2(hp[1]);
                float2 f2 = __half22float2(hp[2]);
                float2 f3 = __half22float2(hp[3]);
                acc[0] += vj * f0.x; acc[1] += vj * f0.y;
                acc[2] += vj * f1.x; acc[3] += vj * f1.y;
                acc[4] += vj * f2.x; acc[5] += vj * f2.y;
                acc[6] += vj * f3.x; acc[7] += vj * f3.y;
            }
        }
    }

    size_t ob = (size_t)row * 32 + (size_t)(li * 2);   // float4 index
    nt_store4((float4*)y + ob,     make_float4(acc[0], acc[1], acc[2], acc[3]));
    nt_store4((float4*)y + ob + 1, make_float4(acc[4], acc[5], acc[6], acc[7]));

    if (WRITE_SHADOW) {
        __half2 h2[4];
        h2[0] = __floats2half2_rn(acc[0], acc[1]);
        h2[1] = __floats2half2_rn(acc[2], acc[3]);
        h2[2] = __floats2half2_rn(acc[4], acc[5]);
        h2[3] = __floats2half2_rn(acc[6], acc[7]);
        yh[(size_t)row * 16 + li] = *reinterpret_cast<float4*>(h2);
    }
}

// ---------------------------------------------------------------------------
// Final total: T = S0 + S1 + S2 + S3 (pure streaming -> fully nontemporal)
// ---------------------------------------------------------------------------
__global__ void total_kernel(const float4* __restrict__ s0,
                             const float4* __restrict__ s1,
                             const float4* __restrict__ s2,
                             const float4* __restrict__ s3,
                             float4* __restrict__ t,
                             size_t n4) {
    size_t stride = (size_t)gridDim.x * blockDim.x;
    for (size_t i = (size_t)blockIdx.x * blockDim.x + threadIdx.x; i < n4; i += stride) {
        float4 a = nt_load4(s0 + i), b = nt_load4(s1 + i);
        float4 c = nt_load4(s2 + i), d = nt_load4(s3 + i);
        float4 o;
        o.x = a.x + b.x + c.x + d.x;
        o.y = a.y + b.y + c.y + d.y;
        o.z = a.z + b.z + c.z + d.z;
        o.w = a.w + b.w + c.w + d.w;
        nt_store4(t + i, o);
    }
}

extern "C" void kernel_launch(void* const* d_in, const int* in_sizes, int n_in,
                              void* d_out, int out_size, void* d_ws, size_t ws_size,
                              hipStream_t stream) {
    const float* item_emb = (const float*)d_in[0];
    const int*   adj_rows = (const int*)d_in[1];
    const int*   adj_cols = (const int*)d_in[2];
    const float* adj_vals = (const float*)d_in[3];

    const size_t NH = (size_t)in_sizes[0];      // N * 128
    const int    E  = in_sizes[1];              // 1,600,000
    const int    N  = (int)(NH / HIDDEN);       // 100,000

    // d_out layout: [ total | S0 | S1 | S2 | S3 ], each NH floats
    float* T  = (float*)d_out;
    float* S0 = T + NH;
    float* S1 = S0 + NH;
    float* S2 = S1 + NH;
    float* S3 = S2 + NH;

    // Scratch placement inside d_out (stream-order-disjoint lifetimes):
    //   shA (T region):  X0h during L1, then S2h during L3; T written last.
    //   shB (S3 region): S1h during L2; dead before L3 writes fp32 S3.
    //   rank (S1 region): used during build only; dead before L1 writes S1.
    float4* shA  = (float4*)T;
    float4* shB  = (float4*)S3;
    int*    rank = (int*)S1;                    // E ints = 6.4 MB << 51 MB

    // Workspace layout — byte-identical footprint to the baseline kernel.
    char* ws = (char*)d_ws;
    int*   row_ptr = (int*)ws;                       ws += ((size_t)(N + 1) * 4 + 15) & ~15ull;
    int*   counts  = (int*)ws;                       ws += ((size_t)N * 4 + 15) & ~15ull;
    int2*  colval  = (int2*)ws;                      // E*8 bytes (old csr_col+csr_val)

    const int nb = (N + SCAN_TILE - 1) / SCAN_TILE;  // 98 scan blocks
    int* block_sums = (int*)(colval + E) - nb;       // tail of colval, dead before scatter

    // ---- CSR build (no atomics in scatter: rank captured during hist) ----
    {
        int block = 256;
        int gridN = min((N + block - 1) / block, 4096);
        int gridE = min((E + block - 1) / block, 8192);
        zero_counts<<<gridN, block, 0, stream>>>(counts, N);
        hist_kernel<<<gridE, block, 0, stream>>>(adj_rows, counts, rank, E);
        scan_partial_sums<<<nb, SCAN_BLOCK, 0, stream>>>(counts, block_sums, N);
        scan_block_offsets<<<1, SCAN_BLOCK, 0, stream>>>(block_sums, row_ptr, nb, N);
        scan_apply<<<nb, SCAN_BLOCK, 0, stream>>>(counts, block_sums, row_ptr, N);
        scatter_kernel<<<gridE, block, 0, stream>>>(adj_rows, adj_cols, adj_vals,
                                                    row_ptr, rank, colval, E);
    }

    // ---- S0 copy + fp16(item_emb) shadow ----
    {
        size_t n8 = NH / 8;
        int block = 256;
        int grid = (int)min((n8 + block - 1) / block, (size_t)8192);
        convert_copy<<<grid, block, 0, stream>>>((const float4*)item_emb,
                                                 (float4*)S0, shA, n8);
    }

    // ---- SpMM layers (fp16 gather, fp32 accumulate/output) ----
    {
        int block = 256;                       // 16 rows per block (16 lanes each)
        int grid = (N * 16 + block - 1) / block;
        // L1: gather X0h (shA) -> S1 fp32 (overwrites dead rank) + S1h (shB)
        spmm_h16<true><<<grid, block, 0, stream>>>(row_ptr, colval, shA, S1, shB, N);
        // L2: gather S1h (shB) -> S2 fp32 + S2h (shA, over dead X0h)
        spmm_h16<true><<<grid, block, 0, stream>>>(row_ptr, colval, shB, S2, shA, N);
        // L3: gather S2h (shA) -> S3 fp32 (overwrites dead S1h region)
        spmm_h16<false><<<grid, block, 0, stream>>>(row_ptr, colval, shA, S3, nullptr, N);
    }

    // ---- T = S0 + S1 + S2 + S3 (overwrites dead S2h region) ----
    {
        size_t n4 = NH / 4;
        int block = 256;
        int grid = (int)min((n4 + block - 1) / block, (size_t)8192);
        total_kernel<<<grid, block, 0, stream>>>((const float4*)S0, (const float4*)S1,
                                                 (const float4*)S2, (const float4*)S3,
                                                 (float4*)T, n4);
    }
}